// Round 14
// baseline (30.337 us; speedup 1.0000x reference)
//
#include <hip/hip_runtime.h>

#define NQ   10
#define NL   4
#define NCL  10
#define PI_F 3.14159265358979f

typedef float f2 __attribute__((ext_vector_type(2)));

// ---- forced VOP3P packed-f32 (validated R13) ----
__device__ __forceinline__ f2 pk_mul2(f2 a, f2 b) {
    f2 d; asm("v_pk_mul_f32 %0, %1, %2" : "=v"(d) : "v"(a), "v"(b)); return d;
}
__device__ __forceinline__ f2 pk_fma2(f2 a, f2 b, f2 c) {   // a*b + c
    f2 d; asm("v_pk_fma_f32 %0, %1, %2, %3" : "=v"(d) : "v"(a), "v"(b), "v"(c)); return d;
}
__device__ __forceinline__ f2 pk_add2(f2 a, f2 b) {
    f2 d; asm("v_pk_add_f32 %0, %1, %2" : "=v"(d) : "v"(a), "v"(b)); return d;
}

__device__ __forceinline__ float bcastf(float v, int l) {
    return __int_as_float(__builtin_amdgcn_readlane(__float_as_int(v), l));
}
__device__ __forceinline__ float bperm(int byteaddr, float v) {
    return __int_as_float(__builtin_amdgcn_ds_bpermute(byteaddr, __float_as_int(v)));
}

// Cross-lane xor-butterfly fetch (validated R5-R13).
template<int M>
__device__ __forceinline__ float xlane(float v) {
    if constexpr (M == 1) {
        return __int_as_float(__builtin_amdgcn_update_dpp(
            __float_as_int(v), __float_as_int(v), 0xB1, 0xF, 0xF, false));
    } else if constexpr (M == 2) {
        return __int_as_float(__builtin_amdgcn_update_dpp(
            __float_as_int(v), __float_as_int(v), 0x4E, 0xF, 0xF, false));
    } else if constexpr (M == 4) {
        return __int_as_float(__builtin_amdgcn_ds_swizzle(
            __float_as_int(v), 0x101F));
    } else if constexpr (M == 8) {
        return __int_as_float(__builtin_amdgcn_update_dpp(
            __float_as_int(v), __float_as_int(v), 0x128, 0xF, 0xF, false));
    } else if constexpr (M == 16) {
        auto r = __builtin_amdgcn_permlane16_swap(
            (unsigned)__float_as_int(v), (unsigned)__float_as_int(v), false, false);
        return __int_as_float((int)(r[0] ^ r[1] ^ (unsigned)__float_as_int(v)));
    } else {
        auto r = __builtin_amdgcn_permlane32_swap(
            (unsigned)__float_as_int(v), (unsigned)__float_as_int(v), false, false);
        return __int_as_float((int)(r[0] ^ r[1] ^ (unsigned)__float_as_int(v)));
    }
}
template<int M>
__device__ __forceinline__ f2 xlane2(f2 v) {
    f2 r; r.x = xlane<M>(v.x); r.y = xlane<M>(v.y); return r;
}

// RY on a lane-bit wire, 8 regs, batched fetch-then-compute (amortizes DS latency).
template<int M>
__device__ __forceinline__ void xwire8(float c, float s, int lane, f2 (&sc)[8]) {
    const float se = (lane & M) ? s : -s;
    const f2 c2 = {c, c}, se2 = {se, se};
    f2 t[8];
    #pragma unroll
    for (int r = 0; r < 8; ++r) t[r] = xlane2<M>(sc[r]);
    #pragma unroll
    for (int r = 0; r < 8; ++r) sc[r] = pk_fma2(se2, t[r], pk_mul2(c2, sc[r]));
}

__device__ __forceinline__ f2 bsum2(f2 v) {
    v = pk_add2(v, xlane2<1 >(v));
    v = pk_add2(v, xlane2<2 >(v));
    v = pk_add2(v, xlane2<4 >(v));
    v = pk_add2(v, xlane2<8 >(v));
    v = pk_add2(v, xlane2<16>(v));
    v = pk_add2(v, xlane2<32>(v));
    return v;
}

// Layout: TWO waves per element (block = 128 threads, one element per block).
// Wave bit W = qubit 0 (perm-invariant: src_q0 = q0, so the CNOT perm is wave-local).
// Register bits r0..r2 = qubits 1..3 (8 f2 regs); lane bits = qubits 4..9.
__global__ __launch_bounds__(128, 4)
void qnn_kernel(const float* __restrict__ x,
                const float* __restrict__ W_pre,
                const float* __restrict__ b_pre,
                const float* __restrict__ weights,
                const float* __restrict__ W_post,
                const float* __restrict__ b_post,
                float* __restrict__ out, int batch)
{
    __shared__ f2 xch[2][2][8][64];   // [pingpong][W][r][lane] = 16 KB
    __shared__ float sq[2][NCL];

    const int tid  = threadIdx.x;
    const int lane = tid & 63;
    const int W    = tid >> 6;        // 0 or 1, wave-uniform
    const int b    = blockIdx.x;      // one element per block, grid == batch

    // 50 half-angle cos/sin pairs (per wave, redundant).
    float cw = 0.0f, sw = 0.0f;
    if (lane < (NL + 1) * NQ) {
        float th = 0.5f * weights[lane];
        __sincosf(th, &sw, &cw);
    }

    // h = x @ W_pre.T + b_pre (uniform addresses).
    float xv[NQ];
    #pragma unroll
    for (int k = 0; k < NQ; ++k) xv[k] = x[b * NQ + k];
    float h[NQ];
    #pragma unroll
    for (int j = 0; j < NQ; ++j) {
        float acc = b_pre[j];
        #pragma unroll
        for (int k = 0; k < NQ; ++k)
            acc = fmaf(xv[k], W_pre[j * NQ + k], acc);
        h[j] = acc;
    }
    float z[NQ - 1];
    #pragma unroll
    for (int i = 0; i < NQ - 1; ++i) z[i] = (PI_F - h[i]) * (PI_F - h[i + 1]);

    // Lane/wave-constant angle part: h0 (W), h4..h9 + z4..z8 (lanes).
    float A = W ? -h[0] : h[0];
    #pragma unroll
    for (int i = 0; i < 6; ++i)
        A += ((lane >> i) & 1) ? -h[4 + i] : h[4 + i];
    #pragma unroll
    for (int j = 0; j < 5; ++j)
        A += (((lane >> j) ^ (lane >> (j + 1))) & 1) ? -z[4 + j] : z[4 + j];
    const float zw0 = W ? -z[0] : z[0];            // z0 pair (q0,q1): sign W^r0
    const float zl3 = (lane & 1) ? -z[3] : z[3];   // z3 pair (q3,q4): sign r2^l0

    // State init: (1/32) e^{-i ang}.
    f2 sc[8];
    #pragma unroll
    for (int r = 0; r < 8; ++r) {
        float ang = A;
        ang += (r & 1) ? -h[1] : h[1];
        ang += (r & 2) ? -h[2] : h[2];
        ang += (r & 4) ? -h[3] : h[3];
        ang += (r & 1) ? -zw0 : zw0;
        ang += ((r ^ (r >> 1)) & 1) ? -z[1] : z[1];          // q1^q2
        ang += (((r >> 1) ^ (r >> 2)) & 1) ? -z[2] : z[2];   // q2^q3
        ang += (r & 4) ? -zl3 : zl3;                         // q3^q4
        float sn, cn;
        __sincosf(ang, &sn, &cn);
        sc[r].x = 0.03125f * cn;
        sc[r].y = -0.03125f * sn;
    }

    // Perm lane part: src_l = ((l ^ (l<<1)) & 0x3F) ^ r2.
    const int plb = (lane ^ (lane << 1)) & 0x3F;
    const int pa0 = plb << 2;
    const int pa1 = (plb ^ 1) << 2;
    int pp = 0;

    #pragma clang loop unroll(disable)
    for (int l = 0; l <= NL; ++l) {
        if (l > 0) {
            // Wave-local perm: src_r = ((r ^ (r<<1)) & 7) ^ W (compile-time per branch).
            f2 np[8];
            if (W == 0) {
                #pragma unroll
                for (int r = 0; r < 8; ++r) {
                    const int rp = (r ^ (r << 1)) & 7;
                    const int pa = (r < 4) ? pa0 : pa1;
                    np[r].x = bperm(pa, sc[rp].x);
                    np[r].y = bperm(pa, sc[rp].y);
                }
            } else {
                #pragma unroll
                for (int r = 0; r < 8; ++r) {
                    const int rp = ((r ^ (r << 1)) & 7) ^ 1;
                    const int pa = (r < 4) ? pa0 : pa1;
                    np[r].x = bperm(pa, sc[rp].x);
                    np[r].y = bperm(pa, sc[rp].y);
                }
            }
            #pragma unroll
            for (int r = 0; r < 8; ++r) sc[r] = np[r];
        }

        const int base = l * NQ;

        // Register wires: qubits 1..3 (r bits 0..2).
        #pragma unroll
        for (int w = 0; w < 3; ++w) {
            const float c = bcastf(cw, base + 1 + w);
            const float s = bcastf(sw, base + 1 + w);
            const f2 c2 = {c, c}, s2 = {s, s}, ns2 = {-s, -s};
            #pragma unroll
            for (int r = 0; r < 8; ++r) {
                if (r & (1 << w)) continue;
                const int q = r | (1 << w);
                f2 a0 = sc[r], a1 = sc[q];
                sc[r] = pk_fma2(ns2, a1, pk_mul2(c2, a0));   // c*a0 - s*a1
                sc[q] = pk_fma2(s2,  a0, pk_mul2(c2, a1));   // s*a0 + c*a1
            }
        }

        // Lane wires: qubits 4..9 (masks 1..32).
        xwire8<1 >(bcastf(cw, base + 4), bcastf(sw, base + 4), lane, sc);
        xwire8<2 >(bcastf(cw, base + 5), bcastf(sw, base + 5), lane, sc);
        xwire8<4 >(bcastf(cw, base + 6), bcastf(sw, base + 6), lane, sc);
        xwire8<8 >(bcastf(cw, base + 7), bcastf(sw, base + 7), lane, sc);
        xwire8<16>(bcastf(cw, base + 8), bcastf(sw, base + 8), lane, sc);
        xwire8<32>(bcastf(cw, base + 9), bcastf(sw, base + 9), lane, sc);

        // Wave wire: qubit 0 — the ONLY cross-wave exchange (5 total).
        {
            const float c = bcastf(cw, base + 0);
            const float s = bcastf(sw, base + 0);
            #pragma unroll
            for (int r = 0; r < 8; ++r) xch[pp][W][r][lane] = sc[r];
            __syncthreads();
            const float se = W ? s : -s;
            const f2 c2 = {c, c}, se2 = {se, se};
            #pragma unroll
            for (int r = 0; r < 8; ++r) {
                f2 t = xch[pp][W ^ 1][r][lane];
                sc[r] = pk_fma2(se2, t, pk_mul2(c2, sc[r]));
            }
            pp ^= 1;
        }
    }

    // Probabilities and per-wave q_k partials.
    float P = 0.0f, p0 = 0.0f, p1 = 0.0f, p2 = 0.0f;
    #pragma unroll
    for (int r = 0; r < 8; ++r) {
        f2 qq = pk_mul2(sc[r], sc[r]);
        float pr = qq.x + qq.y;
        P  += pr;
        p0 += (r & 1) ? -pr : pr;   // qubit 1
        p1 += (r & 2) ? -pr : pr;   // qubit 2
        p2 += (r & 4) ? -pr : pr;   // qubit 3
    }
    f2 qa = bsum2((f2){p0, p1});
    f2 qb = bsum2((f2){p2, p2});
    // Walsh transform of P over lanes: lane 2^j holds S for qubit 4+j.
    {
        float t;
        t = xlane<1 >(P); P = t + ((lane & 1 ) ? -P : P);
        t = xlane<2 >(P); P = t + ((lane & 2 ) ? -P : P);
        t = xlane<4 >(P); P = t + ((lane & 4 ) ? -P : P);
        t = xlane<8 >(P); P = t + ((lane & 8 ) ? -P : P);
        t = xlane<16>(P); P = t + ((lane & 16) ? -P : P);
        t = xlane<32>(P); P = t + ((lane & 32) ? -P : P);
    }
    const float T  = bcastf(P, 0);
    const float s4 = bcastf(P, 1),  s5 = bcastf(P, 2),  s6 = bcastf(P, 4);
    const float s7 = bcastf(P, 8),  s8 = bcastf(P, 16), s9 = bcastf(P, 32);

    if (lane == 0) {
        sq[W][0] = W ? -T : T;   // qubit 0 lives on the wave bit
        sq[W][1] = qa.x; sq[W][2] = qa.y; sq[W][3] = qb.x;
        sq[W][4] = s4; sq[W][5] = s5; sq[W][6] = s6;
        sq[W][7] = s7; sq[W][8] = s8; sq[W][9] = s9;
    }
    __syncthreads();

    if (W == 0 && lane < NCL) {
        float o = b_post[lane];
        #pragma unroll
        for (int k = 0; k < NCL; ++k)
            o = fmaf(sq[0][k] + sq[1][k], W_post[lane * NQ + k], o);
        out[b * NCL + lane] = o;
    }
}

extern "C" void kernel_launch(void* const* d_in, const int* in_sizes, int n_in,
                              void* d_out, int out_size, void* d_ws, size_t ws_size,
                              hipStream_t stream) {
    const float* x       = (const float*)d_in[0];
    const float* W_pre   = (const float*)d_in[1];
    const float* b_pre   = (const float*)d_in[2];
    const float* weights = (const float*)d_in[3];
    const float* W_post  = (const float*)d_in[4];
    const float* b_post  = (const float*)d_in[5];
    float* outp = (float*)d_out;
    int batch = in_sizes[0] / NQ;
    qnn_kernel<<<batch, 128, 0, stream>>>(x, W_pre, b_pre, weights, W_post, b_post, outp, batch);
}